// Round 8
// baseline (372.506 us; speedup 1.0000x reference)
//
#include <hip/hip_runtime.h>
#include <hip/hip_fp16.h>
#include <math.h>

#define SDE_B 16384
#define SDE_S 16
#define SDE_STEPS 50
#define SDE_L 128
#define SDE_DT 0.02f
#define SDE_SQRT_DT 0.14142135623730951f
#define SDE_TEMP 20.0f
#define LOG2E 1.44269504088896340736f
#define LN2 0.69314718055994530942f
#define SC2 (2.0f * LOG2E)          /* pre-scale so tanh arg feeds exp2 directly */
#define CT (SDE_TEMP * LOG2E)       /* hazard arg scale */

typedef float f32x2 __attribute__((ext_vector_type(2)));

#if __has_builtin(__builtin_amdgcn_exp2f)
__device__ __forceinline__ float fexp2(float x) { return __builtin_amdgcn_exp2f(x); }
#else
__device__ __forceinline__ float fexp2(float x) { return __exp2f(x); }
#endif

#if __has_builtin(__builtin_amdgcn_logf)
__device__ __forceinline__ float flog2(float x) { return __builtin_amdgcn_logf(x); }
#else
__device__ __forceinline__ float flog2(float x) { return __log2f(x); }
#endif

#if __has_builtin(__builtin_amdgcn_rcpf)
__device__ __forceinline__ float frcp(float x) { return __builtin_amdgcn_rcpf(x); }
#else
__device__ __forceinline__ float frcp(float x) { return 1.0f / x; }
#endif

#if __has_builtin(__builtin_amdgcn_fmed3f)
__device__ __forceinline__ float fmed3(float x, float lo, float hi) {
    return __builtin_amdgcn_fmed3f(x, lo, hi);
}
#else
__device__ __forceinline__ float fmed3(float x, float lo, float hi) {
    return fminf(fmaxf(x, lo), hi);
}
#endif

// wave-uniform float -> SGPR
__device__ __forceinline__ float uni(float v) {
#if __has_builtin(__builtin_amdgcn_readfirstlane)
    return __int_as_float(__builtin_amdgcn_readfirstlane(__float_as_int(v)));
#else
    return v;
#endif
}

// stable softplus: max(y,0) + log(1+exp(-|y|))
__device__ __forceinline__ float softplus_fast(float y) {
    float m = fmaxf(y, 0.0f);
    float e = fexp2(-fabsf(y) * LOG2E);
    return fmaf(LN2, flog2(1.0f + e), m);
}

// DPP with compile-time control (mov_dpp requires an immediate)
template <int CTL>
__device__ __forceinline__ float dpp_mv(float v) {
#if __has_builtin(__builtin_amdgcn_mov_dpp)
    return __int_as_float(__builtin_amdgcn_mov_dpp(__float_as_int(v), CTL, 0xF, 0xF, true));
#else
    return v;
#endif
}

// packed 8-lane reduction over the q-group (lane = s*8+q): quad xor1,
// quad xor2, then row_half_mirror (q -> 7-q, crossing the quad boundary).
// All DPP: full VALU rate, no LDS. Every lane of the 8 ends with the sum.
__device__ __forceinline__ f32x2 oct_sum2(f32x2 v) {
#if __has_builtin(__builtin_amdgcn_mov_dpp)
    f32x2 w;
    w.x = dpp_mv<0xB1>(v.x);  w.y = dpp_mv<0xB1>(v.y);   // quad_perm xor 1
    v += w;
    w.x = dpp_mv<0x4E>(v.x);  w.y = dpp_mv<0x4E>(v.y);   // quad_perm xor 2
    v += w;
    w.x = dpp_mv<0x141>(v.x); w.y = dpp_mv<0x141>(v.y);  // row_half_mirror
    v += w;
    return v;
#else
    v.x += __shfl_xor(v.x, 1, 64); v.y += __shfl_xor(v.y, 1, 64);
    v.x += __shfl_xor(v.x, 2, 64); v.y += __shfl_xor(v.y, 2, 64);
    v.x += __shfl_xor(v.x, 4, 64); v.y += __shfl_xor(v.y, 4, 64);
    return v;
#endif
}

__device__ __forceinline__ float fixnum(float v) {
    if (isnan(v)) return 0.0f;
    if (isinf(v)) return v > 0.0f ? 3.4028234663852886e38f : -3.4028234663852886e38f;
    return v;
}

// R15: stop fighting the register allocator (R6/R7: hints+pins only caused
// scratch spill at a stubborn 64-VGPR budget). Instead make the working
// set FIT 64 VGPRs: 8 lanes per sim x 8 hidden units per lane (was 4x16).
// Weight invariants drop 80->32 VGPRs; total live ~56 < 64 -> no remat,
// no spill, and 8 waves/SIMD become legal (2x latency hiding).
// Block = 128 threads = 2 waves = 1 batch elem (wave wv owns sims
// wv*8..wv*8+7); lane = s*8+q, units j = 8i+q. Reduction over the 8-lane
// q-group is 3 DPP stages (xor1, xor2, half-mirror). Cross-wave stats
// merged once at the end via a 16-slot LDS buffer + __syncthreads.
// tanh(p) = 1 - 2/(1+exp2(p*2log2e)): weights/zw pre-scaled, "1 - 2*"
// folded into w2' = -2*w2, sum(w2) in the accumulator base.
__global__ void __launch_bounds__(128) sde_kernel(
    const float* __restrict__ z,  const float* __restrict__ W1,
    const float* __restrict__ b1, const float* __restrict__ W2,
    const float* __restrict__ b2, const float* __restrict__ Wb,
    const float* __restrict__ bb, const float* __restrict__ Wn,
    const float* __restrict__ bn, const float* __restrict__ osc,
    const float* __restrict__ obias, const float* __restrict__ noise,
    float* __restrict__ out)
{
    const int lane = threadIdx.x & 63;
    const int wv = threadIdx.x >> 6;      // 0/1: sims 0-7 / 8-15
    const int b = blockIdx.x;
    const int s = lane >> 3;              // sim within wave, 0..7
    const int q = lane & 7;               // hidden-eighth, 0..7

    const float* zr = z + (size_t)b * SDE_L;

    // --- setup: lane l computes zW1 entry for hidden unit j = l ---
    // (each wave computes all 64 redundantly; needed for the shuffles below)
    float accz = b1[lane];
    {
        const float* wrow = W1 + lane * 130 + 2;
        #pragma unroll
        for (int m = 0; m < SDE_L; m += 2) {
            float2 w = *(const float2*)(wrow + m);
            accz = fmaf(zr[m], w.x, accz);
            accz = fmaf(zr[m + 1], w.y, accz);
        }
    }
    accz *= SC2;   // pre-scaled for exp2-tanh

    // --- boundary / ndt: 128-dot reduced over the wave (redundant per wave) ---
    float zb0 = zr[2 * lane], zb1 = zr[2 * lane + 1];
    float pb = fmaf(zb0, Wb[2 * lane], zb1 * Wb[2 * lane + 1]);
    float pn = fmaf(zb0, Wn[2 * lane], zb1 * Wn[2 * lane + 1]);
    #pragma unroll
    for (int off = 32; off > 0; off >>= 1) {
        pb += __shfl_xor(pb, off, 64);
        pn += __shfl_xor(pn, off, 64);
    }
    // wave-uniform scalars -> SGPRs
    const float Hh = uni(CT * (0.5f * (softplus_fast(pb + bb[0]) + 0.3f)));
    const float ndt = uni(softplus_fast(pn + bn[0]) + 0.05f);

    // --- this lane's 8 hidden units (j = 8i+q) as f32 pairs: (i=2p, 2p+1) ---
    f32x2 zw2[4], wx2[4], wt2[4], wa2[4], wb2[4];
    float S2a = 0.0f, S2b = 0.0f;
    #pragma unroll
    for (int p = 0; p < 4; ++p) {
        int j0 = 16 * p + q, j1 = 16 * p + 8 + q;
        zw2[p].x = __shfl(accz, j0, 64);
        zw2[p].y = __shfl(accz, j1, 64);
        float2 wa0 = *(const float2*)(W1 + j0 * 130);  // {w1x, w1t}
        float2 wa1 = *(const float2*)(W1 + j1 * 130);
        wx2[p].x = wa0.x * SC2; wx2[p].y = wa1.x * SC2;
        wt2[p].x = wa0.y * SC2; wt2[p].y = wa1.y * SC2;
        float a0w = W2[j0], a1w = W2[j1];
        float b0w = W2[64 + j0], b1w = W2[64 + j1];
        S2a += a0w + a1w;
        S2b += b0w + b1w;
        wa2[p].x = -2.0f * a0w; wa2[p].y = -2.0f * a1w;
        wb2[p].x = -2.0f * b0w; wb2[p].y = -2.0f * b1w;
    }
    // per-lane accumulator bases: oct-sum over 8 lanes yields b2 + full sums
    const float a0base = fmaf(0.125f, b2[0], S2a);
    const float a1base = fmaf(0.125f, b2[1], S2b);

    // noise addressing: pure int32 offsets (max index ~13.1M < 2^31)
    const int noff = b * SDE_S + (wv * 8 + s);

    float x = 0.0f, surv = 1.0f, ert = 0.0f, ecs = 0.0f;
    float t = 0.0f;
    const f32x2 one2 = {1.0f, 1.0f};
    float nz_cur = noise[noff];   // k=0 preload

    for (int k = 0; k < SDE_STEPS; ++k) {
        // prefetch k+1 (consumed next iteration: full iteration of latency
        // cover); k is scalar so kn*(B*S) stays on the SALU / saddr path
        int kn = (k + 1 < SDE_STEPS) ? k + 1 : k;
        float nz_nxt = noise[kn * (SDE_B * SDE_S) + noff];

        f32x2 acc0; acc0.x = a0base; acc0.y = 0.0f;   // base folded into init
        f32x2 acc1; acc1.x = a1base; acc1.y = 0.0f;
        #pragma unroll
        for (int p = 0; p < 4; ++p) {
            // 2 units per slot: v_pk_fma_f32 chain for pre-activations
            f32x2 pr = x * wx2[p] + (t * wt2[p] + zw2[p]);
            f32x2 e; e.x = fexp2(pr.x); e.y = fexp2(pr.y);
            f32x2 d = e + one2;                 // v_pk_add_f32
            f32x2 g; g.x = frcp(d.x); g.y = frcp(d.y);
            // h_i = 1 - 2*g_i folded: acc += g*(-2*w2); base carries sum(w2)
            acc0 += g * wa2[p];                 // v_pk_fma_f32
            acc1 += g * wb2[p];                 // v_pk_fma_f32
        }
        f32x2 ab;
        ab.x = acc0.x + acc0.y;
        ab.y = acc1.x + acc1.y;
        ab = oct_sum2(ab);
        // identical on all 8 lanes of the q-group -> state stays consistent
        float drift = fmed3(ab.x, -5.0f, 5.0f);
        // diff = softplus(a1) + 0.1; fold (sp + 0.1)*sqrt_dt into one fma
        float sp = softplus_fast(ab.y);
        float diffs = fmaf(sp, SDE_SQRT_DT, 0.1f * SDE_SQRT_DT);
        x = fmaf(drift, SDE_DT, fmaf(diffs, nz_cur, x));
        x = fmed3(x, -10.0f, 10.0f);
        // hz = sigmoid(TEMP*(|x|-half_b)) = 1/(1+exp2(Hh - CT*|x|))
        float e = fexp2(fmaf(fabsf(x), -CT, Hh));
        float hz = fminf(frcp(1.0f + e), 0.99f);
        float cross = surv * hz;
        surv = surv - cross;            // == surv*(1-hz)
        t += SDE_DT;                    // t is now (k+1)*DT
        ert = fmaf(cross, t, ert);
        ecs += __builtin_copysignf(cross, x);   // v_bfi sign transfer
        nz_cur = nz_nxt;
    }

    ert += surv;                    // * (STEPS*DT) = 1.0
    // sum(cross) = 1 - surv  =>  ecorr + surv*0.5 = (1 + ecs) * 0.5
    float corr = (1.0f + ecs) * 0.5f;
    float rt = ert + ndt;           // seconds; x1000 applied after stats

    // --- stats over 16 sims, split 8+8 across the two waves: merge via LDS ---
    __shared__ float rt_lds[SDE_S], cr_lds[SDE_S];
    if (q == 0) {
        rt_lds[wv * 8 + s] = rt;
        cr_lds[wv * 8 + s] = corr;
    }
    __syncthreads();
    if (wv == 0) {
        float rtv = (lane < 16) ? rt_lds[lane] : 0.0f;
        float cv  = (lane < 16) ? cr_lds[lane] : 0.0f;
        float sr = rtv, scr = cv;
        #pragma unroll
        for (int off = 8; off > 0; off >>= 1) {
            sr += __shfl_xor(sr, off, 64);
            scr += __shfl_xor(scr, off, 64);
        }
        float mean = sr * (1.0f / 16.0f);
        float d = rtv - mean;
        float vv = (lane < 16) ? d * d : 0.0f;
        #pragma unroll
        for (int off = 8; off > 0; off >>= 1) vv += __shfl_xor(vv, off, 64);

        if (lane == 0) {
            float std_ms = sqrtf(vv * (1.0f / 15.0f)) * 1000.0f + 0.001f;
            float o0 = fmaf(mean * 1000.0f, osc[0], obias[0]);
            float o1 = fmaf(std_ms, osc[1], obias[1]);
            float o2 = fmaf(scr * (1.0f / 16.0f), osc[2], obias[2]);
            out[b * 3 + 0] = fixnum(o0);
            out[b * 3 + 1] = fixnum(o1);
            out[b * 3 + 2] = fixnum(o2);
        }
    }
}

extern "C" void kernel_launch(void* const* d_in, const int* in_sizes, int n_in,
                              void* d_out, int out_size, void* d_ws, size_t ws_size,
                              hipStream_t stream) {
    const float* z     = (const float*)d_in[0];
    const float* W1    = (const float*)d_in[1];
    const float* b1    = (const float*)d_in[2];
    const float* W2    = (const float*)d_in[3];
    const float* b2    = (const float*)d_in[4];
    const float* Wb    = (const float*)d_in[5];
    const float* bb    = (const float*)d_in[6];
    const float* Wn    = (const float*)d_in[7];
    const float* bn    = (const float*)d_in[8];
    const float* osc   = (const float*)d_in[9];
    const float* obias = (const float*)d_in[10];
    const float* noise = (const float*)d_in[11];
    float* out = (float*)d_out;

    dim3 grid(SDE_B), block(128);
    sde_kernel<<<grid, block, 0, stream>>>(z, W1, b1, W2, b2, Wb, bb, Wn, bn,
                                           osc, obias, noise, out);
}

// Round 10
// 311.664 us; speedup vs baseline: 1.1952x; 1.1952x over previous
//
#include <hip/hip_runtime.h>
#include <hip/hip_fp16.h>
#include <math.h>

#define SDE_B 16384
#define SDE_S 16
#define SDE_STEPS 50
#define SDE_L 128
#define SDE_DT 0.02f
#define SDE_SQRT_DT 0.14142135623730951f
#define SDE_TEMP 20.0f
#define LOG2E 1.44269504088896340736f
#define LN2 0.69314718055994530942f
#define SC2 (2.0f * LOG2E)          /* pre-scale so tanh arg feeds exp2 directly */
#define CT (SDE_TEMP * LOG2E)       /* hazard arg scale */

typedef float f32x2 __attribute__((ext_vector_type(2)));

#if __has_builtin(__builtin_amdgcn_exp2f)
__device__ __forceinline__ float fexp2(float x) { return __builtin_amdgcn_exp2f(x); }
#else
__device__ __forceinline__ float fexp2(float x) { return __exp2f(x); }
#endif

#if __has_builtin(__builtin_amdgcn_logf)
__device__ __forceinline__ float flog2(float x) { return __builtin_amdgcn_logf(x); }
#else
__device__ __forceinline__ float flog2(float x) { return __log2f(x); }
#endif

#if __has_builtin(__builtin_amdgcn_rcpf)
__device__ __forceinline__ float frcp(float x) { return __builtin_amdgcn_rcpf(x); }
#else
__device__ __forceinline__ float frcp(float x) { return 1.0f / x; }
#endif

#if __has_builtin(__builtin_amdgcn_fmed3f)
__device__ __forceinline__ float fmed3(float x, float lo, float hi) {
    return __builtin_amdgcn_fmed3f(x, lo, hi);
}
#else
__device__ __forceinline__ float fmed3(float x, float lo, float hi) {
    return fminf(fmaxf(x, lo), hi);
}
#endif

// wave-uniform float -> SGPR
__device__ __forceinline__ float uni(float v) {
#if __has_builtin(__builtin_amdgcn_readfirstlane)
    return __int_as_float(__builtin_amdgcn_readfirstlane(__float_as_int(v)));
#else
    return v;
#endif
}

// stable softplus: max(y,0) + log(1+exp(-|y|))
__device__ __forceinline__ float softplus_fast(float y) {
    float m = fmaxf(y, 0.0f);
    float e = fexp2(-fabsf(y) * LOG2E);
    return fmaf(LN2, flog2(1.0f + e), m);
}

// DPP quad_perm with compile-time control (mov_dpp requires an immediate)
template <int CTL>
__device__ __forceinline__ float dpp_qp(float v) {
#if __has_builtin(__builtin_amdgcn_mov_dpp)
    return __int_as_float(__builtin_amdgcn_mov_dpp(__float_as_int(v), CTL, 0xF, 0xF, true));
#else
    return v;
#endif
}

// packed quad reduction: sums both halves of v over the 4-lane quad
// (lanes grouped as sim*4+q) via DPP quad_perm; 2 movs + 1 pk_add per stage
__device__ __forceinline__ f32x2 quad_sum2(f32x2 v) {
#if __has_builtin(__builtin_amdgcn_mov_dpp)
    f32x2 w;
    w.x = dpp_qp<0xB1>(v.x); w.y = dpp_qp<0xB1>(v.y);  // quad_perm xor 1
    v += w;
    w.x = dpp_qp<0x4E>(v.x); w.y = dpp_qp<0x4E>(v.y);  // quad_perm xor 2
    v += w;
    return v;
#else
    v.x += __shfl_xor(v.x, 1, 64); v.y += __shfl_xor(v.y, 1, 64);
    v.x += __shfl_xor(v.x, 2, 64); v.y += __shfl_xor(v.y, 2, 64);
    return v;
#endif
}

__device__ __forceinline__ float fixnum(float v) {
    if (isnan(v)) return 0.0f;
    if (isinf(v)) return v > 0.0f ? 3.4028234663852886e38f : -3.4028234663852886e38f;
    return v;
}

// One wave per batch element b. 64 lanes = 16 sims x 4 hidden-quarters.
// lane = s*4 + q: sim s, hidden units j = 4*i + q, i in [0,16).
// R16: R8 falsified the occupancy/spill theories -- per-instruction cost is
// FLAT (~6 cyc-equiv) across occupancy 3.3-5 waves/SIMD, spill or not;
// R8's regression was the epilogue paid 2x per batch elem. So: revert to
// the R2 champion structure (1 wave/batch, lowest inst count) + keep the
// verified-safe shavings (packed DPP quad-reduce, copysign-ecs, folded acc
// base) + probe the last untested residual component: noise-load latency.
// Depth-2 prefetch (load k+2, 3-reg rotation) covers ~900-cyc HBM/L3
// latency with ~2 iterations of work; costs +1 VGPR, same 1 load/step.
// NO launch-bounds hints, NO asm pins (R4/R6/R7: all neutral-to-harmful).
// tanh(p) = 1 - 2/(1+exp2(p*2log2e)): weights/zw pre-scaled, "1 - 2*"
// folded into w2' = -2*w2, sum(w2) in the accumulator base.
__global__ void __launch_bounds__(256) sde_kernel(
    const float* __restrict__ z,  const float* __restrict__ W1,
    const float* __restrict__ b1, const float* __restrict__ W2,
    const float* __restrict__ b2, const float* __restrict__ Wb,
    const float* __restrict__ bb, const float* __restrict__ Wn,
    const float* __restrict__ bn, const float* __restrict__ osc,
    const float* __restrict__ obias, const float* __restrict__ noise,
    float* __restrict__ out)
{
    const int lane = threadIdx.x & 63;
    const int wv = threadIdx.x >> 6;
    const int b = blockIdx.x * 4 + wv;
    const int s = lane >> 2;
    const int q = lane & 3;

    const float* zr = z + (size_t)b * SDE_L;

    // --- setup: lane l computes zW1 entry for hidden unit j = l ---
    float accz = b1[lane];
    {
        const float* wrow = W1 + lane * 130 + 2;
        #pragma unroll
        for (int m = 0; m < SDE_L; m += 2) {
            float2 w = *(const float2*)(wrow + m);
            accz = fmaf(zr[m], w.x, accz);
            accz = fmaf(zr[m + 1], w.y, accz);
        }
    }
    accz *= SC2;   // pre-scaled for exp2-tanh

    // --- boundary / ndt: 128-dot reduced over the wave ---
    float zb0 = zr[2 * lane], zb1 = zr[2 * lane + 1];
    float pb = fmaf(zb0, Wb[2 * lane], zb1 * Wb[2 * lane + 1]);
    float pn = fmaf(zb0, Wn[2 * lane], zb1 * Wn[2 * lane + 1]);
    #pragma unroll
    for (int off = 32; off > 0; off >>= 1) {
        pb += __shfl_xor(pb, off, 64);
        pn += __shfl_xor(pn, off, 64);
    }
    // wave-uniform scalars -> SGPRs
    const float Hh = uni(CT * (0.5f * (softplus_fast(pb + bb[0]) + 0.3f)));
    const float ndt = uni(softplus_fast(pn + bn[0]) + 0.05f);

    // --- this lane's 16 hidden units (j = 4i+q) as f32 pairs: (i=2p, 2p+1) ---
    f32x2 zw2[8], wx2[8], wt2[8], wa2[8], wb2[8];
    float S2a = 0.0f, S2b = 0.0f;
    #pragma unroll
    for (int p = 0; p < 8; ++p) {
        int j0 = 4 * (2 * p) + q, j1 = 4 * (2 * p + 1) + q;
        zw2[p].x = __shfl(accz, j0, 64);
        zw2[p].y = __shfl(accz, j1, 64);
        float2 wa0 = *(const float2*)(W1 + j0 * 130);  // {w1x, w1t}
        float2 wa1 = *(const float2*)(W1 + j1 * 130);
        wx2[p].x = wa0.x * SC2; wx2[p].y = wa1.x * SC2;
        wt2[p].x = wa0.y * SC2; wt2[p].y = wa1.y * SC2;
        float a0w = W2[j0], a1w = W2[j1];
        float b0w = W2[64 + j0], b1w = W2[64 + j1];
        S2a += a0w + a1w;
        S2b += b0w + b1w;
        wa2[p].x = -2.0f * a0w; wa2[p].y = -2.0f * a1w;
        wb2[p].x = -2.0f * b0w; wb2[p].y = -2.0f * b1w;
    }
    // per-lane accumulator bases: quad-sum over 4 lanes yields b2 + full sums
    const float a0base = fmaf(0.25f, b2[0], S2a);
    const float a1base = fmaf(0.25f, b2[1], S2b);

    // noise addressing: pure int32 offsets (max index ~13.1M < 2^31)
    const int noff = b * SDE_S + s;

    float x = 0.0f, surv = 1.0f, ert = 0.0f, ecs = 0.0f;
    float t = 0.0f;
    const f32x2 one2 = {1.0f, 1.0f};
    // depth-2 noise prefetch pipeline: cur (k), n1 (k+1); n2 loaded in-loop
    float nz_cur = noise[noff];                          // k=0
    float nz_n1  = noise[(SDE_B * SDE_S) + noff];        // k=1

    for (int k = 0; k < SDE_STEPS; ++k) {
        // issue load for k+2: two full iterations of latency cover
        int kn = (k + 2 < SDE_STEPS) ? k + 2 : SDE_STEPS - 1;
        float nz_n2 = noise[kn * (SDE_B * SDE_S) + noff];

        f32x2 acc0; acc0.x = a0base; acc0.y = 0.0f;   // base folded into init
        f32x2 acc1; acc1.x = a1base; acc1.y = 0.0f;
        #pragma unroll
        for (int p = 0; p < 8; ++p) {
            // 2 units per slot: v_pk_fma_f32 chain for pre-activations
            f32x2 pr = x * wx2[p] + (t * wt2[p] + zw2[p]);
            f32x2 e; e.x = fexp2(pr.x); e.y = fexp2(pr.y);
            f32x2 d = e + one2;                 // v_pk_add_f32
            f32x2 g; g.x = frcp(d.x); g.y = frcp(d.y);
            // h_i = 1 - 2*g_i folded: acc += g*(-2*w2); base carries sum(w2)
            acc0 += g * wa2[p];                 // v_pk_fma_f32
            acc1 += g * wb2[p];                 // v_pk_fma_f32
        }
        f32x2 ab;
        ab.x = acc0.x + acc0.y;
        ab.y = acc1.x + acc1.y;
        ab = quad_sum2(ab);
        // identical on all 4 lanes of the quad -> state stays consistent
        float drift = fmed3(ab.x, -5.0f, 5.0f);
        // diff = softplus(a1) + 0.1; fold (sp + 0.1)*sqrt_dt into one fma
        float sp = softplus_fast(ab.y);
        float diffs = fmaf(sp, SDE_SQRT_DT, 0.1f * SDE_SQRT_DT);
        x = fmaf(drift, SDE_DT, fmaf(diffs, nz_cur, x));
        x = fmed3(x, -10.0f, 10.0f);
        // hz = sigmoid(TEMP*(|x|-half_b)) = 1/(1+exp2(Hh - CT*|x|))
        float e = fexp2(fmaf(fabsf(x), -CT, Hh));
        float hz = fminf(frcp(1.0f + e), 0.99f);
        float cross = surv * hz;
        surv = surv - cross;            // == surv*(1-hz)
        t += SDE_DT;                    // t is now (k+1)*DT
        ert = fmaf(cross, t, ert);
        ecs += __builtin_copysignf(cross, x);   // v_bfi sign transfer
        nz_cur = nz_n1;
        nz_n1 = nz_n2;
    }

    ert += surv;                    // * (STEPS*DT) = 1.0
    // sum(cross) = 1 - surv  =>  ecorr + surv*0.5 = (1 + ecs) * 0.5
    float corr = (1.0f + ecs) * 0.5f;
    float rt = ert + ndt;           // seconds; x1000 applied after stats

    // --- stats over 16 sims (mask quad-redundant copies to q==0) ---
    float sr = (q == 0) ? rt : 0.0f;
    float scr = (q == 0) ? corr : 0.0f;
    #pragma unroll
    for (int off = 32; off > 0; off >>= 1) {
        sr += __shfl_xor(sr, off, 64);
        scr += __shfl_xor(scr, off, 64);
    }
    float mean = sr * (1.0f / 16.0f);
    float d = rt - mean;
    float vv = (q == 0) ? d * d : 0.0f;
    #pragma unroll
    for (int off = 32; off > 0; off >>= 1) vv += __shfl_xor(vv, off, 64);

    if (lane == 0) {
        float std_ms = sqrtf(vv * (1.0f / 15.0f)) * 1000.0f + 0.001f;
        float o0 = fmaf(mean * 1000.0f, osc[0], obias[0]);
        float o1 = fmaf(std_ms, osc[1], obias[1]);
        float o2 = fmaf(scr * (1.0f / 16.0f), osc[2], obias[2]);
        out[b * 3 + 0] = fixnum(o0);
        out[b * 3 + 1] = fixnum(o1);
        out[b * 3 + 2] = fixnum(o2);
    }
}

extern "C" void kernel_launch(void* const* d_in, const int* in_sizes, int n_in,
                              void* d_out, int out_size, void* d_ws, size_t ws_size,
                              hipStream_t stream) {
    const float* z     = (const float*)d_in[0];
    const float* W1    = (const float*)d_in[1];
    const float* b1    = (const float*)d_in[2];
    const float* W2    = (const float*)d_in[3];
    const float* b2    = (const float*)d_in[4];
    const float* Wb    = (const float*)d_in[5];
    const float* bb    = (const float*)d_in[6];
    const float* Wn    = (const float*)d_in[7];
    const float* bn    = (const float*)d_in[8];
    const float* osc   = (const float*)d_in[9];
    const float* obias = (const float*)d_in[10];
    const float* noise = (const float*)d_in[11];
    float* out = (float*)d_out;

    dim3 grid(SDE_B / 4), block(256);
    sde_kernel<<<grid, block, 0, stream>>>(z, W1, b1, W2, b2, Wb, bb, Wn, bn,
                                           osc, obias, noise, out);
}